// Round 4
// baseline (201.697 us; speedup 1.0000x reference)
//
#include <hip/hip_runtime.h>
#include <hip/hip_bf16.h>

// CTRNN fused kernel for MI355X (gfx950).
// B=8192, D=512, N=512, K=D+N=1024, 6 unfolds, dt=0.1, tau=1.
// state' = 0.9*state + 0.1*tanh(inputs@W_in + state@W_rec + bias)
//
// R4 = R3 + explicit depth-1 group double-buffer on B-fragment loads
//      (16 loads in flight while MFMA-ing previous 16), with
//      __launch_bounds__(512,1) so the register cap is ~512 not 128.
// R2 tried this pipeline under launch_bounds(512,2) -> 128-VGPR cap ->
// scratch spills (WRITE_SIZE 143MB). Grid=256 gives 1 block/CU regardless,
// so capping at 128 regs bought nothing. R3 (no pipeline) achieved only
// 9.7 TB/s of L2 W-read BW (28% of ceiling) -> latency-bound on B-loads.

#define BB 8192
#define DD 512
#define NN 512
#define KK 1024
#define BM 32
#define NTHREADS 512
#define NUNFOLD 6

using short8 = __attribute__((ext_vector_type(8))) short;
using f32x4  = __attribute__((ext_vector_type(4))) float;

__device__ __forceinline__ unsigned short f2bf(float f) {
    // round-to-nearest-even f32 -> bf16 (finite inputs only)
    unsigned int u = __float_as_uint(f);
    u += 0x7fffu + ((u >> 16) & 1u);
    return (unsigned short)(u >> 16);
}

// Pack W (f32, [k=1024][n=512] row-major) into bf16 fragment-major layout:
// chunk index = (ct*32 + ks)*64 + lane, each chunk = 8 bf16 = 16B, where
//   n = ct*16 + (lane&15),  k = ks*32 + (lane>>4)*8 + e   (e = 0..7)
// A wave loading fragment (ct, ks) reads one contiguous 1KB block.
__global__ void w_to_frag(const float* __restrict__ W,
                          unsigned short* __restrict__ WTf) {
    int gid  = blockIdx.x * blockDim.x + threadIdx.x;  // 0..65535
    int lane = gid & 63;
    int frag = gid >> 6;        // ct*32 + ks
    int ks   = frag & 31;
    int ct   = frag >> 5;
    int n  = ct * 16 + (lane & 15);
    int k0 = ks * 32 + (lane >> 4) * 8;
    unsigned short v[8];
#pragma unroll
    for (int e = 0; e < 8; ++e)
        v[e] = f2bf(W[(size_t)(k0 + e) * NN + n]);
    *reinterpret_cast<short8*>(WTf + (size_t)gid * 8) =
        *reinterpret_cast<const short8*>(v);
}

__global__ __launch_bounds__(NTHREADS, 1)
void ctrnn_fused(const float* __restrict__ inputs,
                 const float* __restrict__ state,
                 const float* __restrict__ bias,
                 const unsigned short* __restrict__ WTf,
                 float* __restrict__ out) {
    // bf16 A-tile, [r][c], XOR-swizzled byte addr
    __shared__ __align__(16) char Alds[BM * DD * 2];  // 32 KB

    const int tid  = threadIdx.x;
    const int lane = tid & 63;
    const int wv   = tid >> 6;        // wave 0..7, owns cols [wv*64, wv*64+64)
    const int row0 = blockIdx.x * BM;
    const int l15  = lane & 15;
    const int l4   = lane >> 4;       // 0..3
    const int lane_k = l4 * 8;

    const short8* WTf8 = reinterpret_cast<const short8*>(WTf);
    // b(nt, ksg) = Bw[(nt*32 + ksg)*64]   (ksg: 0..15 = W_in, 16..31 = W_rec)
    const short8* Bw = WTf8 + (size_t)(wv * 4) * 32 * 64 + lane;

    auto lda = [&](int mt, int k) -> short8 {
        int r = mt * 16 + l15;
        int byte = (r * 1024 + k * 2) ^ ((r & 7) << 4);
        return *reinterpret_cast<const short8*>(&Alds[byte]);
    };
    auto stage = [&](const float* __restrict__ src) {
        const float4* s4 = reinterpret_cast<const float4*>(src);
#pragma unroll
        for (int i = 0; i < 8; ++i) {
            int q  = tid + i * NTHREADS;  // 0..4095 = r*128 + c4
            int r  = q >> 7;
            int c4 = q & 127;
            float4 v = s4[q];
            uint2 p;
            p.x = (unsigned int)f2bf(v.x) | ((unsigned int)f2bf(v.y) << 16);
            p.y = (unsigned int)f2bf(v.z) | ((unsigned int)f2bf(v.w) << 16);
            int byte = (r * 1024 + c4 * 8) ^ ((r & 7) << 4);
            *reinterpret_cast<uint2*>(&Alds[byte]) = p;
        }
    };

    f32x4 acc[2][4];

    // One K=512 GEMM pass with a depth-1 group double-buffer on B loads:
    // while MFMA-ing group g (4 ks, 16 fragments), the 16 loads of group
    // g+1 are in flight. acc must be pre-initialized by caller.
    auto gemm = [&](int ksbase) {
        short8 bb[2][4][4];  // [parity][kk][nt] : 128 VGPRs
#pragma unroll
        for (int kk = 0; kk < 4; ++kk)
#pragma unroll
            for (int nt = 0; nt < 4; ++nt)
                bb[0][kk][nt] = Bw[(size_t)(nt * 32 + ksbase + kk) * 64];
#pragma unroll
        for (int g = 0; g < 4; ++g) {
            if (g < 3) {
#pragma unroll
                for (int kk = 0; kk < 4; ++kk)
#pragma unroll
                    for (int nt = 0; nt < 4; ++nt)
                        bb[(g + 1) & 1][kk][nt] =
                            Bw[(size_t)(nt * 32 + ksbase + (g + 1) * 4 + kk) * 64];
            }
#pragma unroll
            for (int kk = 0; kk < 4; ++kk) {
                int k = (g * 4 + kk) * 32 + lane_k;
                short8 a0 = lda(0, k);
                short8 a1 = lda(1, k);
#pragma unroll
                for (int nt = 0; nt < 4; ++nt) {
                    acc[0][nt] = __builtin_amdgcn_mfma_f32_16x16x32_bf16(
                        a0, bb[g & 1][kk][nt], acc[0][nt], 0, 0, 0);
                    acc[1][nt] = __builtin_amdgcn_mfma_f32_16x16x32_bf16(
                        a1, bb[g & 1][kk][nt], acc[1][nt], 0, 0, 0);
                }
            }
        }
    };

    // ---------------- phase 1: proj = inputs @ W_in + bias ----------------
    stage(inputs + (size_t)row0 * DD);

    // f32 master state at C-layout positions; issue loads early so they
    // overlap the proj GEMM (first use is after gemm(0)).
    f32x4 sreg[2][4];
#pragma unroll
    for (int mt = 0; mt < 2; ++mt)
#pragma unroll
        for (int nt = 0; nt < 4; ++nt)
#pragma unroll
            for (int j = 0; j < 4; ++j)
                sreg[mt][nt][j] =
                    state[(size_t)(row0 + mt * 16 + l4 * 4 + j) * NN +
                          (wv * 64 + nt * 16 + l15)];

    __syncthreads();

#pragma unroll
    for (int mt = 0; mt < 2; ++mt)
#pragma unroll
        for (int nt = 0; nt < 4; ++nt)
            acc[mt][nt] = f32x4{0.f, 0.f, 0.f, 0.f};
    gemm(0);

    f32x4 proj[2][4];
#pragma unroll
    for (int nt = 0; nt < 4; ++nt) {
        float bv = bias[wv * 64 + nt * 16 + l15];
#pragma unroll
        for (int mt = 0; mt < 2; ++mt)
#pragma unroll
            for (int j = 0; j < 4; ++j)
                proj[mt][nt][j] = acc[mt][nt][j] + bv;
    }

    // ---------------- phase 2: stage state into LDS as bf16 ----------------
    __syncthreads();  // proj GEMM LDS reads done, safe to overwrite
    stage(state + (size_t)row0 * NN);
    __syncthreads();

    // ---------------- phase 3: 6 unfolds ----------------
    for (int u = 0; u < NUNFOLD; ++u) {
#pragma unroll
        for (int mt = 0; mt < 2; ++mt)
#pragma unroll
            for (int nt = 0; nt < 4; ++nt)
                acc[mt][nt] = proj[mt][nt];  // pre-init with inputs@W_in + b
        gemm(16);
        __syncthreads();  // all LDS reads of old state done

#pragma unroll
        for (int mt = 0; mt < 2; ++mt)
#pragma unroll
            for (int nt = 0; nt < 4; ++nt)
#pragma unroll
                for (int j = 0; j < 4; ++j) {
                    float x = acc[mt][nt][j];
                    float t = 1.f - 2.f / (__expf(2.f * x) + 1.f);  // tanh(x)
                    float s = sreg[mt][nt][j] * 0.9f + 0.1f * t;
                    sreg[mt][nt][j] = s;
                    int r = mt * 16 + l4 * 4 + j;
                    int c = wv * 64 + nt * 16 + l15;
                    int byte = (r * 1024 + c * 2) ^ ((r & 7) << 4);
                    *reinterpret_cast<unsigned short*>(&Alds[byte]) = f2bf(s);
                }
        __syncthreads();  // new state visible before next unfold's reads
    }

    // ---------------- epilogue: out = (state, state) ----------------
#pragma unroll
    for (int mt = 0; mt < 2; ++mt)
#pragma unroll
        for (int nt = 0; nt < 4; ++nt)
#pragma unroll
            for (int j = 0; j < 4; ++j) {
                size_t r = (size_t)(row0 + mt * 16 + l4 * 4 + j);
                int c = wv * 64 + nt * 16 + l15;
                float s = sreg[mt][nt][j];
                out[r * NN + c] = s;
                out[(size_t)BB * NN + r * NN + c] = s;
            }
}

extern "C" void kernel_launch(void* const* d_in, const int* in_sizes, int n_in,
                              void* d_out, int out_size, void* d_ws, size_t ws_size,
                              hipStream_t stream) {
    const float* inputs = (const float*)d_in[0];
    const float* state  = (const float*)d_in[1];
    const float* W      = (const float*)d_in[2];   // (1024, 512) row-major
    const float* bias   = (const float*)d_in[3];   // (512,)
    float* out = (float*)d_out;                    // 2 * 8192*512 f32
    unsigned short* WTf = (unsigned short*)d_ws;   // bf16 fragment-major, 1 MB

    w_to_frag<<<(KK / 32) * (NN / 16) * 64 / 512, 512, 0, stream>>>(W, WTf);
    ctrnn_fused<<<BB / BM, NTHREADS, 0, stream>>>(inputs, state, bias, WTf, out);
}

// Round 5
// 124.217 us; speedup vs baseline: 1.6237x; 1.6237x over previous
//
#include <hip/hip_runtime.h>
#include <hip/hip_bf16.h>

// CTRNN fused kernel for MI355X (gfx950).
// B=8192, D=512, N=512, K=D+N=1024, 6 unfolds, dt=0.1, tau=1.
// state' = 0.9*state + 0.1*tanh(inputs@W_in + state@W_rec + bias)
//
// R5: W fragments are staged global->LDS via __builtin_amdgcn_global_load_lds
// (16B width) into a 3-slot rolling buffer with counted s_waitcnt vmcnt(N)
// (T3/T4 pattern). In-flight W data costs ZERO VGPRs, so the pipeline can be
// deep without the register spills that killed R2/R4 (both pinned at 128
// VGPRs + 143MB scratch traffic). W slabs are wave-private -> no barriers in
// the K-loop. LDS = 32KB A-tile + 96KB W = 128KB (also forces 1 block/CU,
// aligning the compiler's occupancy heuristic with our actual occupancy).

#define BB 8192
#define DD 512
#define NN 512
#define BM 32
#define NTHREADS 512
#define NUNFOLD 6

using short8 = __attribute__((ext_vector_type(8))) short;
using f32x4  = __attribute__((ext_vector_type(4))) float;
typedef unsigned int u32;

__device__ __forceinline__ unsigned short f2bf(float f) {
    // round-to-nearest-even f32 -> bf16 (finite inputs only)
    unsigned int u = __float_as_uint(f);
    u += 0x7fffu + ((u >> 16) & 1u);
    return (unsigned short)(u >> 16);
}

// Pack W (f32, [k=1024][n=512] row-major) into bf16 fragment-major layout:
// chunk index = (ct*32 + ks)*64 + lane, each chunk = 8 bf16 = 16B, where
//   n = ct*16 + (lane&15),  k = ks*32 + (lane>>4)*8 + e   (e = 0..7)
// A wave loading fragment (ct, ks) reads one contiguous 1KB block, and
// global_load_lds's fixed lane-order LDS write (base + lane*16) lands each
// lane's 16B exactly where that lane ds_read_b128's it back.
__global__ void w_to_frag(const float* __restrict__ W,
                          unsigned short* __restrict__ WTf) {
    int gid  = blockIdx.x * blockDim.x + threadIdx.x;  // 0..65535
    int lane = gid & 63;
    int frag = gid >> 6;        // ct*32 + ks
    int ks   = frag & 31;
    int ct   = frag >> 5;
    int n  = ct * 16 + (lane & 15);
    int k0 = ks * 32 + (lane >> 4) * 8;
    unsigned short v[8];
#pragma unroll
    for (int e = 0; e < 8; ++e)
        v[e] = f2bf(W[(size_t)(k0 + e) * NN + n]);
    *reinterpret_cast<short8*>(WTf + (size_t)gid * 8) =
        *reinterpret_cast<const short8*>(v);
}

__global__ __launch_bounds__(NTHREADS, 1)
void ctrnn_fused(const float* __restrict__ inputs,
                 const float* __restrict__ state,
                 const float* __restrict__ bias,
                 const unsigned short* __restrict__ WTf,
                 float* __restrict__ out) {
    // bf16 A-tile, [r][c], XOR-swizzled byte addr
    __shared__ __align__(16) char Alds[BM * DD * 2];       // 32 KB
    // W slabs: [slot 0..2][wv 0..7][nt 0..3][1KB]
    __shared__ __align__(16) char Wlds[3 * 8 * 4 * 1024];  // 96 KB

    const int tid  = threadIdx.x;
    const int lane = tid & 63;
    const int wv   = tid >> 6;        // wave 0..7, owns cols [wv*64, wv*64+64)
    const int row0 = blockIdx.x * BM;
    const int l15  = lane & 15;
    const int l4   = lane >> 4;       // 0..3
    const int lane_k = l4 * 8;

    // this wave's global fragment base (nt=0, ksg=0), per-lane 16B chunk
    const char* wg = (const char*)WTf +
                     ((size_t)(wv * 4) * 32 * 64 + (size_t)lane) * 16;
    // this wave's LDS slab base (slot 0, nt 0)
    char* wbuf = Wlds + wv * 4096;

    // issue the 4 fragment loads (nt=0..3) of frag-column ksg into `slot`
    auto issueW = [&](int slot, int ksg) {
#pragma unroll
        for (int nt = 0; nt < 4; ++nt)
            __builtin_amdgcn_global_load_lds(
                (const __attribute__((address_space(1))) u32*)
                    (wg + (size_t)ksg * 1024 + (size_t)nt * 32768),
                (__attribute__((address_space(3))) u32*)
                    (wbuf + slot * 32768 + nt * 1024),
                16, 0, 0);
    };

    auto lda = [&](int mt, int k) -> short8 {
        int r = mt * 16 + l15;
        int byte = (r * 1024 + k * 2) ^ ((r & 7) << 4);
        return *reinterpret_cast<const short8*>(&Alds[byte]);
    };
    auto stage = [&](const float* __restrict__ src) {
        const float4* s4 = reinterpret_cast<const float4*>(src);
#pragma unroll
        for (int i = 0; i < 8; ++i) {
            int q  = tid + i * NTHREADS;  // 0..4095 = r*128 + c4
            int r  = q >> 7;
            int c4 = q & 127;
            float4 v = s4[q];
            uint2 p;
            p.x = (unsigned int)f2bf(v.x) | ((unsigned int)f2bf(v.y) << 16);
            p.y = (unsigned int)f2bf(v.z) | ((unsigned int)f2bf(v.w) << 16);
            int byte = (r * 1024 + c4 * 8) ^ ((r & 7) << 4);
            *reinterpret_cast<uint2*>(&Alds[byte]) = p;
        }
    };

    f32x4 acc[2][4];

    // One K=512 GEMM pass. base = 0 (W_in) or 16 (W_rec).
    // 3-slot rolling pipeline: slot ks ready when <=8 newer loads outstanding.
    // acc must be pre-initialized by caller. No barriers inside (W is
    // wave-private; A-tile is read-only for the whole pass).
    auto pass = [&](int base) {
        issueW(0, base);
        issueW(1, base + 1);
        issueW(2, base + 2);
#pragma unroll
        for (int ks = 0; ks < 16; ++ks) {
            if (ks < 14)
                asm volatile("s_waitcnt vmcnt(8)" ::: "memory");
            else if (ks == 14)
                asm volatile("s_waitcnt vmcnt(4)" ::: "memory");
            else
                asm volatile("s_waitcnt vmcnt(0)" ::: "memory");
            const char* sb = wbuf + (ks % 3) * 32768;
            short8 w0 = *reinterpret_cast<const short8*>(sb + 0 * 1024 + lane * 16);
            short8 w1 = *reinterpret_cast<const short8*>(sb + 1 * 1024 + lane * 16);
            short8 w2 = *reinterpret_cast<const short8*>(sb + 2 * 1024 + lane * 16);
            short8 w3 = *reinterpret_cast<const short8*>(sb + 3 * 1024 + lane * 16);
            int k = ks * 32 + lane_k;
            short8 a0 = lda(0, k);
            short8 a1 = lda(1, k);
            acc[0][0] = __builtin_amdgcn_mfma_f32_16x16x32_bf16(a0, w0, acc[0][0], 0, 0, 0);
            acc[1][0] = __builtin_amdgcn_mfma_f32_16x16x32_bf16(a1, w0, acc[1][0], 0, 0, 0);
            acc[0][1] = __builtin_amdgcn_mfma_f32_16x16x32_bf16(a0, w1, acc[0][1], 0, 0, 0);
            acc[1][1] = __builtin_amdgcn_mfma_f32_16x16x32_bf16(a1, w1, acc[1][1], 0, 0, 0);
            acc[0][2] = __builtin_amdgcn_mfma_f32_16x16x32_bf16(a0, w2, acc[0][2], 0, 0, 0);
            acc[1][2] = __builtin_amdgcn_mfma_f32_16x16x32_bf16(a1, w2, acc[1][2], 0, 0, 0);
            acc[0][3] = __builtin_amdgcn_mfma_f32_16x16x32_bf16(a0, w3, acc[0][3], 0, 0, 0);
            acc[1][3] = __builtin_amdgcn_mfma_f32_16x16x32_bf16(a1, w3, acc[1][3], 0, 0, 0);
            if (ks < 13) issueW(ks % 3, base + ks + 3);
        }
    };

    // ---------------- phase 1: proj = inputs @ W_in + bias ----------------
    stage(inputs + (size_t)row0 * DD);

    // f32 master state at C-layout positions; loads overlap the proj GEMM
    // and are drained by the first __syncthreads.
    f32x4 sreg[2][4];
#pragma unroll
    for (int mt = 0; mt < 2; ++mt)
#pragma unroll
        for (int nt = 0; nt < 4; ++nt)
#pragma unroll
            for (int j = 0; j < 4; ++j)
                sreg[mt][nt][j] =
                    state[(size_t)(row0 + mt * 16 + l4 * 4 + j) * NN +
                          (wv * 64 + nt * 16 + l15)];

    __syncthreads();  // A-tile visible; also drains vmcnt to 0 for the pipeline

#pragma unroll
    for (int mt = 0; mt < 2; ++mt)
#pragma unroll
        for (int nt = 0; nt < 4; ++nt)
            acc[mt][nt] = f32x4{0.f, 0.f, 0.f, 0.f};
    pass(0);

    f32x4 proj[2][4];
#pragma unroll
    for (int nt = 0; nt < 4; ++nt) {
        float bv = bias[wv * 64 + nt * 16 + l15];
#pragma unroll
        for (int mt = 0; mt < 2; ++mt)
#pragma unroll
            for (int j = 0; j < 4; ++j)
                proj[mt][nt][j] = acc[mt][nt][j] + bv;
    }

    // ---------------- phase 2: stage state into LDS as bf16 ----------------
    __syncthreads();  // all proj-pass A-reads done, safe to overwrite
    stage(state + (size_t)row0 * NN);
    __syncthreads();

    // ---------------- phase 3: 6 unfolds ----------------
    for (int u = 0; u < NUNFOLD; ++u) {
#pragma unroll
        for (int mt = 0; mt < 2; ++mt)
#pragma unroll
            for (int nt = 0; nt < 4; ++nt)
                acc[mt][nt] = proj[mt][nt];  // pre-init with inputs@W_in + b
        pass(16);
        __syncthreads();  // all LDS reads of old state done

#pragma unroll
        for (int mt = 0; mt < 2; ++mt)
#pragma unroll
            for (int nt = 0; nt < 4; ++nt)
#pragma unroll
                for (int j = 0; j < 4; ++j) {
                    float x = acc[mt][nt][j];
                    float t = 1.f - 2.f / (__expf(2.f * x) + 1.f);  // tanh(x)
                    float s = sreg[mt][nt][j] * 0.9f + 0.1f * t;
                    sreg[mt][nt][j] = s;
                    int r = mt * 16 + l4 * 4 + j;
                    int c = wv * 64 + nt * 16 + l15;
                    int byte = (r * 1024 + c * 2) ^ ((r & 7) << 4);
                    *reinterpret_cast<unsigned short*>(&Alds[byte]) = f2bf(s);
                }
        __syncthreads();  // new state visible before next unfold's reads
    }

    // ---------------- epilogue: out = (state, state) ----------------
#pragma unroll
    for (int mt = 0; mt < 2; ++mt)
#pragma unroll
        for (int nt = 0; nt < 4; ++nt)
#pragma unroll
            for (int j = 0; j < 4; ++j) {
                size_t r = (size_t)(row0 + mt * 16 + l4 * 4 + j);
                int c = wv * 64 + nt * 16 + l15;
                float s = sreg[mt][nt][j];
                out[r * NN + c] = s;
                out[(size_t)BB * NN + r * NN + c] = s;
            }
}

extern "C" void kernel_launch(void* const* d_in, const int* in_sizes, int n_in,
                              void* d_out, int out_size, void* d_ws, size_t ws_size,
                              hipStream_t stream) {
    const float* inputs = (const float*)d_in[0];
    const float* state  = (const float*)d_in[1];
    const float* W      = (const float*)d_in[2];   // (1024, 512) row-major
    const float* bias   = (const float*)d_in[3];   // (512,)
    float* out = (float*)d_out;                    // 2 * 8192*512 f32
    unsigned short* WTf = (unsigned short*)d_ws;   // bf16 fragment-major, 1 MB

    w_to_frag<<<(1024 / 32) * (NN / 16) * 64 / 512, 512, 0, stream>>>(W, WTf);
    ctrnn_fused<<<BB / BM, NTHREADS, 0, stream>>>(inputs, state, bias, WTf, out);
}